// Round 1
// 99.692 us; speedup vs baseline: 1.0236x; 1.0236x over previous
//
#include <hip/hip_runtime.h>

// GATv1-style single-head attention, N=8192, F_in=128, F_out=64, alpha=0.2.
// exp(leakyrelu(s_i + d_j)) is separable per branch; predicate fl(s+d)>0 is
// exactly mono_enc(d) > mono_enc(-s). Sort j by d, prefix tables of e^d*Wh and
// e^{0.2d}*Wh sampled every 8 sorted elements, per-row ballot search + <=7
// residual terms. O(N^2 F) -> O(N(logN+F)).
// HARD CONSTRAINTS (learned r5-r8):
//   - hipLaunchCooperativeKernel aborts harness graph capture (r5).
//   - hipMemsetAsync inside kernel_launch is suspect (r6).
//   - software grid barriers deadlock -> HSA abort (r7). No grid-wide sync.
// R9: pipeline is latency/launch-gap bound (rooflines are ~1-2 us; we are at
// 102 us; top-5 rocprof rows are all harness fillBuffer). Cut 8 dispatches to
// 5: (a) single 8-way LDS rank-merge replaces the 3 global merge rounds
// (position = local idx + sum of 7 independent branchless binary-search
// ranks; keys unique so ranks exact); (b) fuse k3a+k3b into one kernel
// (per-column group sums + dual in-block scan; kills GS1T/GS2T round trip).
// k1_wh / k2a_1024 / k4_out bodies are byte-identical to the proven r8 ones.

typedef unsigned long long ull;

constexpr int N_ROWS = 8192;
constexpr int F_IN   = 128;
constexpr int F_OUT  = 64;
#define LRELU_ALPHA 0.2f

constexpr int SBLK = 8;                  // prefix-table sampling granularity
constexpr int NGRP = N_ROWS / SBLK;      // 1024 groups; tables hold NGRP+1 entries

// workspace layout in floats (~3.2 MB; ws is 256 MiB). Layout kept identical
// to r8 even though GS1T/GS2T/GD1/GD2 are no longer materialized.
constexpr int WS_WH   = 0;                          // Wh row-major [j][c]
constexpr int WS_ESRC = WS_WH + N_ROWS * F_OUT;     // e_src[i]
constexpr int WS_KEYA = WS_ESRC + N_ROWS;           // 8192 ull ping
constexpr int WS_KEYB = WS_KEYA + 2 * N_ROWS;       // 8192 ull pong (final sorted)
constexpr int WS_GS1T = WS_KEYB + 2 * N_ROWS;       // (unused as of r9)
constexpr int WS_GS2T = WS_GS1T + F_OUT * NGRP;     // (unused as of r9)
constexpr int WS_GD1  = WS_GS2T + F_OUT * NGRP;     // (unused as of r9)
constexpr int WS_GD2  = WS_GD1 + NGRP;              // (unused as of r9)
constexpr int WS_P1   = WS_GD2 + NGRP;              // (NGRP+1) x 64, layout [b][c]
constexpr int WS_P2   = WS_P1 + (NGRP + 1) * F_OUT;
constexpr int WS_D1   = WS_P2 + (NGRP + 1) * F_OUT; // NGRP+1
constexpr int WS_D2   = WS_D1 + (NGRP + 1);
static_assert((WS_KEYA % 2) == 0 && (WS_KEYB % 2) == 0, "keys 8B-aligned");

// monotone float<->uint mapping (ascending uint order == ascending float order)
__device__ __forceinline__ unsigned mono_enc(float f) {
  unsigned u = __float_as_uint(f);
  return u ^ ((u & 0x80000000u) ? 0xFFFFFFFFu : 0x80000000u);
}
__device__ __forceinline__ float mono_dec(unsigned e) {
  unsigned u = e ^ ((e & 0x80000000u) ? 0x80000000u : 0xFFFFFFFFu);
  return __uint_as_float(u);
}

// ---------------- K1: Wh = h @ W ; e_src = Wh@a1 ; keys = (enc(Wh@a2), j) ----------------
// grid 512 x 256 threads. 16 rows/block, wave handles 4 rows, lane = output col. (proven)
__global__ __launch_bounds__(256) void k1_wh(const float* __restrict__ h,
                                             const float* __restrict__ W,
                                             const float* __restrict__ a,
                                             float* __restrict__ ws) {
  __shared__ float hlds[16 * F_IN];
  __shared__ float alds[2 * F_OUT];
  const int t = threadIdx.x;
  const int row0 = blockIdx.x * 16;

  const float4* hsrc = (const float4*)(h + (long)row0 * F_IN);
  float4* hd = (float4*)hlds;
  hd[t]       = hsrc[t];
  hd[t + 256] = hsrc[t + 256];
  if (t < 2 * F_OUT) alds[t] = a[t];
  __syncthreads();

  const int wave = t >> 6, lane = t & 63;
  const float* hp = hlds + (wave * 4) * F_IN;
  float acc0 = 0.f, acc1 = 0.f, acc2 = 0.f, acc3 = 0.f;

  #pragma unroll 4
  for (int k4 = 0; k4 < F_IN; k4 += 4) {
    float4 h0 = *(const float4*)(hp + k4);
    float4 h1 = *(const float4*)(hp + F_IN + k4);
    float4 h2 = *(const float4*)(hp + 2 * F_IN + k4);
    float4 h3 = *(const float4*)(hp + 3 * F_IN + k4);
    float w0 = W[(k4 + 0) * F_OUT + lane];
    float w1 = W[(k4 + 1) * F_OUT + lane];
    float w2 = W[(k4 + 2) * F_OUT + lane];
    float w3 = W[(k4 + 3) * F_OUT + lane];
    acc0 = fmaf(h0.x, w0, acc0); acc0 = fmaf(h0.y, w1, acc0);
    acc0 = fmaf(h0.z, w2, acc0); acc0 = fmaf(h0.w, w3, acc0);
    acc1 = fmaf(h1.x, w0, acc1); acc1 = fmaf(h1.y, w1, acc1);
    acc1 = fmaf(h1.z, w2, acc1); acc1 = fmaf(h1.w, w3, acc1);
    acc2 = fmaf(h2.x, w0, acc2); acc2 = fmaf(h2.y, w1, acc2);
    acc2 = fmaf(h2.z, w2, acc2); acc2 = fmaf(h2.w, w3, acc2);
    acc3 = fmaf(h3.x, w0, acc3); acc3 = fmaf(h3.y, w1, acc3);
    acc3 = fmaf(h3.z, w2, acc3); acc3 = fmaf(h3.w, w3, acc3);
  }

  const int grow = row0 + wave * 4;
  float* Wh = ws + WS_WH;
  Wh[(grow + 0) * F_OUT + lane] = acc0;
  Wh[(grow + 1) * F_OUT + lane] = acc1;
  Wh[(grow + 2) * F_OUT + lane] = acc2;
  Wh[(grow + 3) * F_OUT + lane] = acc3;

  const float a1 = alds[lane], a2 = alds[F_OUT + lane];
  float s0 = acc0 * a1, s1 = acc1 * a1, s2 = acc2 * a1, s3 = acc3 * a1;
  float d0 = acc0 * a2, d1 = acc1 * a2, d2 = acc2 * a2, d3 = acc3 * a2;
  #pragma unroll
  for (int off = 32; off; off >>= 1) {
    s0 += __shfl_down(s0, off); s1 += __shfl_down(s1, off);
    s2 += __shfl_down(s2, off); s3 += __shfl_down(s3, off);
    d0 += __shfl_down(d0, off); d1 += __shfl_down(d1, off);
    d2 += __shfl_down(d2, off); d3 += __shfl_down(d3, off);
  }
  if (lane == 0) {
    ws[WS_ESRC + grow + 0] = s0; ws[WS_ESRC + grow + 1] = s1;
    ws[WS_ESRC + grow + 2] = s2; ws[WS_ESRC + grow + 3] = s3;
    ull* keys = (ull*)(ws + WS_KEYA);
    keys[grow + 0] = ((ull)mono_enc(d0) << 32) | (unsigned)(grow + 0);
    keys[grow + 1] = ((ull)mono_enc(d1) << 32) | (unsigned)(grow + 1);
    keys[grow + 2] = ((ull)mono_enc(d2) << 32) | (unsigned)(grow + 2);
    keys[grow + 3] = ((ull)mono_enc(d3) << 32) | (unsigned)(grow + 3);
  }
}

// ---------------- K2: 8 blocks x 1024 threads, bitonic-sort 1024-key runs in LDS ---------
// Exact sort loop from round-3's k23_sort_scan (hardware-proven correct).
__global__ __launch_bounds__(1024) void k2a_1024(ull* __restrict__ keys) {
  __shared__ ull lk[1024];          // 8 KB
  const int t = threadIdx.x;
  const int base = blockIdx.x * 1024;
  lk[t] = keys[base + t];
  __syncthreads();
  for (int k = 2; k <= 1024; k <<= 1) {
    for (int j = k >> 1; j > 0; j >>= 1) {
      int p = t ^ j;
      if (p > t) {
        ull x = lk[t], y = lk[p];
        bool asc = ((t & k) == 0);
        if ((x > y) == asc) { lk[t] = y; lk[p] = x; }
      }
      __syncthreads();
    }
  }
  keys[base + t] = lk[t];
}

// ---------------- K2b (r9): single 8-way rank-merge, sorted runs -> fully sorted ----------
// 16 blocks x 512 threads. Whole key array (64 KB) staged in LDS. Each thread owns one
// element g: final pos = (g & 1023) + sum over the 7 OTHER runs of rank(key in run).
// Keys are globally unique (low 32 bits = j) so strict-< rank is exact and positions are
// a permutation. Rank per run = branchless uniform binary search (Knuth): 10 probes at
// pos+step-1 over the power-of-two run, plus one final probe -> count of elements < key.
// The 7 searches are independent and fully unrolled -> ~7-deep MLP on the LDS chains.
__global__ __launch_bounds__(512) void k2_rank(const ull* __restrict__ src,
                                               ull* __restrict__ dst) {
  __shared__ ull lk[8192];          // 64 KB — all keys
  const int t = threadIdx.x;
  #pragma unroll
  for (int c = 0; c < 16; ++c) lk[c * 512 + t] = src[c * 512 + t];
  __syncthreads();

  const int g = blockIdx.x * 512 + t;
  const ull key = lk[g];
  const int myrun = g >> 10;        // block-uniform (512-blocks are run-aligned)
  int pos = g & 1023;               // rank within own (sorted, unique) run

  #pragma unroll
  for (int r = 0; r < 8; ++r) {
    if (r == myrun) continue;       // uniform branch per block
    const ull* base = lk + (r << 10);
    int p = 0;
    #pragma unroll
    for (int step = 512; step >= 1; step >>= 1)
      p += (base[p + step - 1] < key) ? step : 0;    // p <= 1023 always
    p += (base[p] < key) ? 1 : 0;                    // count in [0,1024]
    pos += p;
  }
  dst[pos] = key;
}

// ---------------- K3 (r9): fused group sums + dual in-block scan -> P1,P2,D1,D2 ----------
// 65 blocks x 1024 threads. Blocks 0..63: column c = blk. Thread t = group g: reads the
// group's 8 sorted keys (64 B contiguous per thread, block streams all keys coalesced;
// same 64 KB broadcast to every block via L2) and gathers Wh[j][c] (L2-resident, ~512 KB
// of 64 B lines per block). Then one dual Hillis-Steele scan (exact k3b pattern) produces
// the exclusive prefix for BOTH e^d and e^{0.2d} tables. Block 64: denominators D1/D2.
// Accumulation order per group (o = 0..7) and scan order identical to r8 -> bitwise-same.
__global__ __launch_bounds__(1024) void k3_tables(float* __restrict__ ws) {
  __shared__ float sa[1024];
  __shared__ float sb[1024];
  const int t = threadIdx.x;
  const int blk = blockIdx.x;
  const ull* K = (const ull*)(ws + WS_KEYB);
  const float* Wh = ws + WS_WH;

  float s1 = 0.f, s2 = 0.f;
  if (blk < 64) {
    const int c = blk;
    const ull* kp = K + (t << 3);
    #pragma unroll
    for (int o = 0; o < SBLK; ++o) {
      ull key = kp[o];
      float d = mono_dec((unsigned)(key >> 32));
      int j = (int)(key & 0xFFFFFFFFu);
      float e1 = __expf(d), e2 = __expf(LRELU_ALPHA * d);
      float v = Wh[j * F_OUT + c];
      s1 = fmaf(e1, v, s1); s2 = fmaf(e2, v, s2);
    }
  } else {
    const ull* kp = K + (t << 3);
    #pragma unroll
    for (int o = 0; o < SBLK; ++o) {
      ull key = kp[o];
      float d = mono_dec((unsigned)(key >> 32));
      s1 += __expf(d); s2 += __expf(LRELU_ALPHA * d);
    }
  }

  const float xa = s1, xb = s2;
  sa[t] = xa; sb[t] = xb;
  __syncthreads();
  for (int off = 1; off < 1024; off <<= 1) {   // Hillis-Steele inclusive scan (x2)
    float ya = (t >= off) ? sa[t - off] : 0.f;
    float yb = (t >= off) ? sb[t - off] : 0.f;
    __syncthreads();
    sa[t] += ya; sb[t] += yb;
    __syncthreads();
  }
  const float ia = sa[t], ib = sb[t];
  const float ea = ia - xa, eb = ib - xb;

  if (blk < 64) {
    const int c = blk;
    ws[WS_P1 + t * F_OUT + c] = ea;
    ws[WS_P2 + t * F_OUT + c] = eb;
    if (t == NGRP - 1) {
      ws[WS_P1 + NGRP * F_OUT + c] = ia;
      ws[WS_P2 + NGRP * F_OUT + c] = ib;
    }
  } else {
    ws[WS_D1 + t] = ea;
    ws[WS_D2 + t] = eb;
    if (t == NGRP - 1) {
      ws[WS_D1 + NGRP] = ia;
      ws[WS_D2 + NGRP] = ib;
    }
  }
}

// ---------------- K4: 3-stage wave-ballot search + table lookup + residual + ELU ---------
// grid 2048 x 256. One wave per row, lane = output column. (proven)
__global__ __launch_bounds__(256) void k4_out(const float* __restrict__ ws,
                                              float* __restrict__ out) {
  const int t = threadIdx.x, wv = t >> 6, lane = t & 63;
  const int i = blockIdx.x * 4 + wv;
  const ull* K = (const ull*)(ws + WS_KEYB);
  const float s = ws[WS_ESRC + i];
  const float ns = (s == 0.0f) ? 0.0f : -s;   // canonicalize -0
  const unsigned Ki = mono_enc(ns);           // m > Ki  <=>  fl(s+d) > 0

  unsigned m1 = (unsigned)(K[lane << 7] >> 32);
  ull bal1 = __ballot(m1 <= Ki);
  int tl;
  if (bal1 == 0ull) {
    tl = 0;
  } else {
    int L1 = 63 - __clzll((long long)bal1);
    int base = L1 << 7;
    unsigned m2 = (unsigned)(K[base + (lane << 1)] >> 32);
    ull bal2 = __ballot(m2 <= Ki);
    int L2 = 63 - __clzll((long long)bal2);
    int p = base + (L2 << 1) + 1;
    unsigned m3 = (unsigned)(K[p] >> 32);
    tl = p + ((m3 <= Ki) ? 1 : 0);
  }
  const int b = tl >> 3, rr = tl & 7;

  float p1 = ws[WS_P1 + b * F_OUT + lane];
  float p2 = ws[WS_P2 + b * F_OUT + lane];
  float d1 = ws[WS_D1 + b], d2 = ws[WS_D2 + b];
  const float p1tot = ws[WS_P1 + NGRP * F_OUT + lane];
  const float d1tot = ws[WS_D1 + NGRP];
  const float* Wh = ws + WS_WH;

  for (int o = 0; o < rr; ++o) {               // <=7 residual elements
    ull key = K[(b << 3) + o];
    float d = mono_dec((unsigned)(key >> 32));
    int j = (int)(key & 0xFFFFFFFFu);
    float e1 = __expf(d), e2 = __expf(LRELU_ALPHA * d);
    float v = Wh[j * F_OUT + lane];            // coalesced 256B row
    p1 = fmaf(e1, v, p1); p2 = fmaf(e2, v, p2);
    d1 += e1; d2 += e2;
  }

  const float es1 = __expf(s), es2 = __expf(LRELU_ALPHA * s);
  const float num = es1 * (p1tot - p1) + es2 * p2;
  const float den = es1 * (d1tot - d1) + es2 * d2;
  const float r = num / den;
  out[i * F_OUT + lane] = (r > 0.f) ? r : (__expf(r) - 1.f);
}

extern "C" void kernel_launch(void* const* d_in, const int* in_sizes, int n_in,
                              void* d_out, int out_size, void* d_ws, size_t ws_size,
                              hipStream_t stream) {
  const float* h = (const float*)d_in[0];
  const float* W = (const float*)d_in[1];
  const float* a = (const float*)d_in[2];
  float* ws = (float*)d_ws;
  float* out = (float*)d_out;
  ull* keyA = (ull*)(ws + WS_KEYA);
  ull* keyB = (ull*)(ws + WS_KEYB);

  hipLaunchKernelGGL(k1_wh,     dim3(N_ROWS / 16), dim3(256),  0, stream, h, W, a, ws);
  hipLaunchKernelGGL(k2a_1024,  dim3(8),           dim3(1024), 0, stream, keyA);
  hipLaunchKernelGGL(k2_rank,   dim3(16),          dim3(512),  0, stream, keyA, keyB);
  hipLaunchKernelGGL(k3_tables, dim3(65),          dim3(1024), 0, stream, ws);
  hipLaunchKernelGGL(k4_out,    dim3(N_ROWS / 4),  dim3(256),  0, stream, ws, out);
}

// Round 2
// 93.831 us; speedup vs baseline: 1.0876x; 1.0625x over previous
//
#include <hip/hip_runtime.h>

// GATv1-style single-head attention, N=8192, F_in=128, F_out=64, alpha=0.2.
// exp(leakyrelu(s_i + d_j)) is separable per branch; predicate fl(s+d)>0 is
// exactly mono_enc(d) > mono_enc(-s). Sort j by d, prefix tables of e^d*Wh and
// e^{0.2d}*Wh sampled every 8 sorted elements, per-row ballot search + <=7
// residual terms. O(N^2 F) -> O(N(logN+F)).
// HARD CONSTRAINTS (learned r5-r8):
//   - hipLaunchCooperativeKernel aborts harness graph capture (r5).
//   - hipMemsetAsync inside kernel_launch is suspect (r6).
//   - software grid barriers deadlock -> HSA abort (r7). No grid-wide sync.
// R9 lesson: launch gaps are ~0.8 us each, NOT ~5 us — the pipeline is
// kernel-execution-bound. R10: replace the whole sort chain (k2a bitonic on
// 8 CUs with 55 barrier rounds + k2_rank) with ONE O(N^2) counting rank-sort
// on all 256 CUs: rank = #{key' < key} over all 8192 keys staged in LDS,
// 16 slices/key, strided pair access (16i+s) -> fixed distinct bank pair per
// slice, 4-lane broadcast, ~2048 b128 DS-instrs/CU ~= 2 us. Keys unique
// (low 32 bits = j) so strict-< rank is an exact permutation; sorted output
// is bitwise identical to r9's -> k3/k4 numerics unchanged.
// Pipeline (4 dispatches): k1_wh -> k2_sort -> k3_tables -> k4_out.

typedef unsigned long long ull;

constexpr int N_ROWS = 8192;
constexpr int F_IN   = 128;
constexpr int F_OUT  = 64;
#define LRELU_ALPHA 0.2f

constexpr int SBLK = 8;                  // prefix-table sampling granularity
constexpr int NGRP = N_ROWS / SBLK;      // 1024 groups; tables hold NGRP+1 entries

// workspace layout in floats (~3.2 MB; ws is 256 MiB). Layout kept identical
// to r8/r9 (GS* slots unused since r9).
constexpr int WS_WH   = 0;                          // Wh row-major [j][c]
constexpr int WS_ESRC = WS_WH + N_ROWS * F_OUT;     // e_src[i]
constexpr int WS_KEYA = WS_ESRC + N_ROWS;           // 8192 ull unsorted
constexpr int WS_KEYB = WS_KEYA + 2 * N_ROWS;       // 8192 ull sorted
constexpr int WS_GS1T = WS_KEYB + 2 * N_ROWS;       // (unused)
constexpr int WS_GS2T = WS_GS1T + F_OUT * NGRP;     // (unused)
constexpr int WS_GD1  = WS_GS2T + F_OUT * NGRP;     // (unused)
constexpr int WS_GD2  = WS_GD1 + NGRP;              // (unused)
constexpr int WS_P1   = WS_GD2 + NGRP;              // (NGRP+1) x 64, layout [b][c]
constexpr int WS_P2   = WS_P1 + (NGRP + 1) * F_OUT;
constexpr int WS_D1   = WS_P2 + (NGRP + 1) * F_OUT; // NGRP+1
constexpr int WS_D2   = WS_D1 + (NGRP + 1);
static_assert((WS_KEYA % 2) == 0 && (WS_KEYB % 2) == 0, "keys 8B-aligned");

// monotone float<->uint mapping (ascending uint order == ascending float order)
__device__ __forceinline__ unsigned mono_enc(float f) {
  unsigned u = __float_as_uint(f);
  return u ^ ((u & 0x80000000u) ? 0xFFFFFFFFu : 0x80000000u);
}
__device__ __forceinline__ float mono_dec(unsigned e) {
  unsigned u = e ^ ((e & 0x80000000u) ? 0x80000000u : 0xFFFFFFFFu);
  return __uint_as_float(u);
}

// ---------------- K1: Wh = h @ W ; e_src = Wh@a1 ; keys = (enc(Wh@a2), j) ----------------
// grid 512 x 256 threads. 16 rows/block, wave handles 4 rows, lane = output col. (proven)
__global__ __launch_bounds__(256) void k1_wh(const float* __restrict__ h,
                                             const float* __restrict__ W,
                                             const float* __restrict__ a,
                                             float* __restrict__ ws) {
  __shared__ float hlds[16 * F_IN];
  __shared__ float alds[2 * F_OUT];
  const int t = threadIdx.x;
  const int row0 = blockIdx.x * 16;

  const float4* hsrc = (const float4*)(h + (long)row0 * F_IN);
  float4* hd = (float4*)hlds;
  hd[t]       = hsrc[t];
  hd[t + 256] = hsrc[t + 256];
  if (t < 2 * F_OUT) alds[t] = a[t];
  __syncthreads();

  const int wave = t >> 6, lane = t & 63;
  const float* hp = hlds + (wave * 4) * F_IN;
  float acc0 = 0.f, acc1 = 0.f, acc2 = 0.f, acc3 = 0.f;

  #pragma unroll 4
  for (int k4 = 0; k4 < F_IN; k4 += 4) {
    float4 h0 = *(const float4*)(hp + k4);
    float4 h1 = *(const float4*)(hp + F_IN + k4);
    float4 h2 = *(const float4*)(hp + 2 * F_IN + k4);
    float4 h3 = *(const float4*)(hp + 3 * F_IN + k4);
    float w0 = W[(k4 + 0) * F_OUT + lane];
    float w1 = W[(k4 + 1) * F_OUT + lane];
    float w2 = W[(k4 + 2) * F_OUT + lane];
    float w3 = W[(k4 + 3) * F_OUT + lane];
    acc0 = fmaf(h0.x, w0, acc0); acc0 = fmaf(h0.y, w1, acc0);
    acc0 = fmaf(h0.z, w2, acc0); acc0 = fmaf(h0.w, w3, acc0);
    acc1 = fmaf(h1.x, w0, acc1); acc1 = fmaf(h1.y, w1, acc1);
    acc1 = fmaf(h1.z, w2, acc1); acc1 = fmaf(h1.w, w3, acc1);
    acc2 = fmaf(h2.x, w0, acc2); acc2 = fmaf(h2.y, w1, acc2);
    acc2 = fmaf(h2.z, w2, acc2); acc2 = fmaf(h2.w, w3, acc2);
    acc3 = fmaf(h3.x, w0, acc3); acc3 = fmaf(h3.y, w1, acc3);
    acc3 = fmaf(h3.z, w2, acc3); acc3 = fmaf(h3.w, w3, acc3);
  }

  const int grow = row0 + wave * 4;
  float* Wh = ws + WS_WH;
  Wh[(grow + 0) * F_OUT + lane] = acc0;
  Wh[(grow + 1) * F_OUT + lane] = acc1;
  Wh[(grow + 2) * F_OUT + lane] = acc2;
  Wh[(grow + 3) * F_OUT + lane] = acc3;

  const float a1 = alds[lane], a2 = alds[F_OUT + lane];
  float s0 = acc0 * a1, s1 = acc1 * a1, s2 = acc2 * a1, s3 = acc3 * a1;
  float d0 = acc0 * a2, d1 = acc1 * a2, d2 = acc2 * a2, d3 = acc3 * a2;
  #pragma unroll
  for (int off = 32; off; off >>= 1) {
    s0 += __shfl_down(s0, off); s1 += __shfl_down(s1, off);
    s2 += __shfl_down(s2, off); s3 += __shfl_down(s3, off);
    d0 += __shfl_down(d0, off); d1 += __shfl_down(d1, off);
    d2 += __shfl_down(d2, off); d3 += __shfl_down(d3, off);
  }
  if (lane == 0) {
    ws[WS_ESRC + grow + 0] = s0; ws[WS_ESRC + grow + 1] = s1;
    ws[WS_ESRC + grow + 2] = s2; ws[WS_ESRC + grow + 3] = s3;
    ull* keys = (ull*)(ws + WS_KEYA);
    keys[grow + 0] = ((ull)mono_enc(d0) << 32) | (unsigned)(grow + 0);
    keys[grow + 1] = ((ull)mono_enc(d1) << 32) | (unsigned)(grow + 1);
    keys[grow + 2] = ((ull)mono_enc(d2) << 32) | (unsigned)(grow + 2);
    keys[grow + 3] = ((ull)mono_enc(d3) << 32) | (unsigned)(grow + 3);
  }
}

// ---------------- K2 (r10): O(N^2) counting rank-sort, one dispatch, all CUs -------------
// 256 blocks x 512 threads. All 8192 keys staged in LDS (64 KB). Block owns 32 keys:
// key idx = blk*32 + (t>>4); slice s = t&15 counts key-pairs p = 16*i + s, i = 0..255
// (b128 read of 2 keys). Bank math: pair p -> byte 16p -> bank-quad 4s%32: 16 slices map
// to 8 quads x 2 addresses = 2-way (free, m136); the 4 lanes sharing s broadcast.
// rank = strict-< count over all keys (unique: low 32 bits = j) -> dst[rank] = key is an
// exact permutation, bitwise-identical to any correct sort of the same keys.
__global__ __launch_bounds__(512) void k2_sort(const ull* __restrict__ src,
                                               ull* __restrict__ dst) {
  __shared__ ull lk[8192];          // 64 KB — all keys
  const int t = threadIdx.x;        // 0..511

  ulonglong2* lkv = (ulonglong2*)lk;
  const ulonglong2* srcv = (const ulonglong2*)src;
  #pragma unroll
  for (int c = 0; c < 8; ++c) lkv[c * 512 + t] = srcv[c * 512 + t];
  __syncthreads();

  const int kidx = (blockIdx.x << 5) + (t >> 4);   // 32 keys per block
  const ull key = lk[kidx];
  const int s = t & 15;

  int cnt = 0;
  const ulonglong2* lk2 = (const ulonglong2*)lk;   // 4096 pairs
  #pragma unroll 8
  for (int i = 0; i < 256; ++i) {
    ulonglong2 v = lk2[(i << 4) | s];
    cnt += (v.x < key) ? 1 : 0;
    cnt += (v.y < key) ? 1 : 0;
  }
  // reduce the 16 slice partials (16-lane groups within the wave)
  cnt += __shfl_down(cnt, 8, 16);
  cnt += __shfl_down(cnt, 4, 16);
  cnt += __shfl_down(cnt, 2, 16);
  cnt += __shfl_down(cnt, 1, 16);
  if (s == 0) dst[cnt] = key;       // cnt = exact global rank in [0, 8192)
}

// ---------------- K3: fused group sums + dual in-block scan -> P1,P2,D1,D2 (r9 proven) ---
// 65 blocks x 1024 threads. Blocks 0..63: column c = blk. Thread t = group g: reads the
// group's 8 sorted keys and gathers Wh[j][c] (L2-resident). Dual Hillis-Steele scan kept
// BITWISE IDENTICAL to the proven version (absmax sits at threshold; no reassociation).
__global__ __launch_bounds__(1024) void k3_tables(float* __restrict__ ws) {
  __shared__ float sa[1024];
  __shared__ float sb[1024];
  const int t = threadIdx.x;
  const int blk = blockIdx.x;
  const ull* K = (const ull*)(ws + WS_KEYB);
  const float* Wh = ws + WS_WH;

  float s1 = 0.f, s2 = 0.f;
  if (blk < 64) {
    const int c = blk;
    const ull* kp = K + (t << 3);
    #pragma unroll
    for (int o = 0; o < SBLK; ++o) {
      ull key = kp[o];
      float d = mono_dec((unsigned)(key >> 32));
      int j = (int)(key & 0xFFFFFFFFu);
      float e1 = __expf(d), e2 = __expf(LRELU_ALPHA * d);
      float v = Wh[j * F_OUT + c];
      s1 = fmaf(e1, v, s1); s2 = fmaf(e2, v, s2);
    }
  } else {
    const ull* kp = K + (t << 3);
    #pragma unroll
    for (int o = 0; o < SBLK; ++o) {
      ull key = kp[o];
      float d = mono_dec((unsigned)(key >> 32));
      s1 += __expf(d); s2 += __expf(LRELU_ALPHA * d);
    }
  }

  const float xa = s1, xb = s2;
  sa[t] = xa; sb[t] = xb;
  __syncthreads();
  for (int off = 1; off < 1024; off <<= 1) {   // Hillis-Steele inclusive scan (x2)
    float ya = (t >= off) ? sa[t - off] : 0.f;
    float yb = (t >= off) ? sb[t - off] : 0.f;
    __syncthreads();
    sa[t] += ya; sb[t] += yb;
    __syncthreads();
  }
  const float ia = sa[t], ib = sb[t];
  const float ea = ia - xa, eb = ib - xb;

  if (blk < 64) {
    const int c = blk;
    ws[WS_P1 + t * F_OUT + c] = ea;
    ws[WS_P2 + t * F_OUT + c] = eb;
    if (t == NGRP - 1) {
      ws[WS_P1 + NGRP * F_OUT + c] = ia;
      ws[WS_P2 + NGRP * F_OUT + c] = ib;
    }
  } else {
    ws[WS_D1 + t] = ea;
    ws[WS_D2 + t] = eb;
    if (t == NGRP - 1) {
      ws[WS_D1 + NGRP] = ia;
      ws[WS_D2 + NGRP] = ib;
    }
  }
}

// ---------------- K4: 3-stage wave-ballot search + table lookup + residual + ELU ---------
// grid 2048 x 256. One wave per row, lane = output column. (proven)
__global__ __launch_bounds__(256) void k4_out(const float* __restrict__ ws,
                                              float* __restrict__ out) {
  const int t = threadIdx.x, wv = t >> 6, lane = t & 63;
  const int i = blockIdx.x * 4 + wv;
  const ull* K = (const ull*)(ws + WS_KEYB);
  const float s = ws[WS_ESRC + i];
  const float ns = (s == 0.0f) ? 0.0f : -s;   // canonicalize -0
  const unsigned Ki = mono_enc(ns);           // m > Ki  <=>  fl(s+d) > 0

  unsigned m1 = (unsigned)(K[lane << 7] >> 32);
  ull bal1 = __ballot(m1 <= Ki);
  int tl;
  if (bal1 == 0ull) {
    tl = 0;
  } else {
    int L1 = 63 - __clzll((long long)bal1);
    int base = L1 << 7;
    unsigned m2 = (unsigned)(K[base + (lane << 1)] >> 32);
    ull bal2 = __ballot(m2 <= Ki);
    int L2 = 63 - __clzll((long long)bal2);
    int p = base + (L2 << 1) + 1;
    unsigned m3 = (unsigned)(K[p] >> 32);
    tl = p + ((m3 <= Ki) ? 1 : 0);
  }
  const int b = tl >> 3, rr = tl & 7;

  float p1 = ws[WS_P1 + b * F_OUT + lane];
  float p2 = ws[WS_P2 + b * F_OUT + lane];
  float d1 = ws[WS_D1 + b], d2 = ws[WS_D2 + b];
  const float p1tot = ws[WS_P1 + NGRP * F_OUT + lane];
  const float d1tot = ws[WS_D1 + NGRP];
  const float* Wh = ws + WS_WH;

  for (int o = 0; o < rr; ++o) {               // <=7 residual elements
    ull key = K[(b << 3) + o];
    float d = mono_dec((unsigned)(key >> 32));
    int j = (int)(key & 0xFFFFFFFFu);
    float e1 = __expf(d), e2 = __expf(LRELU_ALPHA * d);
    float v = Wh[j * F_OUT + lane];            // coalesced 256B row
    p1 = fmaf(e1, v, p1); p2 = fmaf(e2, v, p2);
    d1 += e1; d2 += e2;
  }

  const float es1 = __expf(s), es2 = __expf(LRELU_ALPHA * s);
  const float num = es1 * (p1tot - p1) + es2 * p2;
  const float den = es1 * (d1tot - d1) + es2 * d2;
  const float r = num / den;
  out[i * F_OUT + lane] = (r > 0.f) ? r : (__expf(r) - 1.f);
}

extern "C" void kernel_launch(void* const* d_in, const int* in_sizes, int n_in,
                              void* d_out, int out_size, void* d_ws, size_t ws_size,
                              hipStream_t stream) {
  const float* h = (const float*)d_in[0];
  const float* W = (const float*)d_in[1];
  const float* a = (const float*)d_in[2];
  float* ws = (float*)d_ws;
  float* out = (float*)d_out;
  ull* keyA = (ull*)(ws + WS_KEYA);
  ull* keyB = (ull*)(ws + WS_KEYB);

  hipLaunchKernelGGL(k1_wh,     dim3(N_ROWS / 16), dim3(256),  0, stream, h, W, a, ws);
  hipLaunchKernelGGL(k2_sort,   dim3(256),         dim3(512),  0, stream, keyA, keyB);
  hipLaunchKernelGGL(k3_tables, dim3(65),          dim3(1024), 0, stream, ws);
  hipLaunchKernelGGL(k4_out,    dim3(N_ROWS / 4),  dim3(256),  0, stream, ws, out);
}